// Round 1
// baseline (971.859 us; speedup 1.0000x reference)
//
#include <hip/hip_runtime.h>
#include <math.h>

namespace {

constexpr int kB = 2, kH = 16, kN = 8192, kHD = 128, kJ = 20;
constexpr int kTQ = 64;                         // queries per 256-thread block (4 lanes/query)
constexpr float kScale = 0.08838834764831845f;  // 1/sqrt(128)

__global__ __launch_bounds__(256)
void dsqg_fwd(const float* __restrict__ q, const float* __restrict__ k,
              const float* __restrict__ v, const float* __restrict__ pb,
              const float* __restrict__ se, float* __restrict__ out) {
  constexpr int OFFS[kJ] = {1, 2, 3, 4, 5, 6, 7, 8, 9, 11,
                            13, 15, 16, 23, 32, 64, 128, 256, 512, 1024};
  __shared__ float s_se[kJ * kHD];  // 10 KB: scale_embed, reused by all 64 queries
  __shared__ float s_pb[kJ];

  const int t = threadIdx.x;
  const int bh = blockIdx.y;        // b*H + h
  const int h = bh & (kH - 1);
  const int n = blockIdx.x * kTQ + (t >> 2);  // this thread's query row
  const int part = t & 3;                     // which 32-dim chunk of HD

  // Stage scale_embed + this head's pos_bias column into LDS.
  for (int i = t; i < kJ * kHD; i += 256) s_se[i] = se[i];
  if (t < kJ) s_pb[t] = pb[t * kH + h];
  __syncthreads();

  const size_t base = (size_t)bh * kN * kHD;
  const float4* qrow = (const float4*)(q + base + (size_t)n * kHD + part * 32);
  float4 rq[8];
#pragma unroll
  for (int i = 0; i < 8; ++i) rq[i] = qrow[i];

  // ---- Phase A: scores s_j = sc*(q.k[n-dj] + q.se_j) + pb[j][h], -inf if n<dj
  float sc[kJ];
#pragma unroll
  for (int j = 0; j < kJ; ++j) {
    const int delta = OFFS[j];
    int kr = n - delta;
    kr = kr < 0 ? 0 : kr;  // clamped like the reference; masked below
    const float4* krow = (const float4*)(k + base + (size_t)kr * kHD + part * 32);
    const float4* srow = (const float4*)(s_se + j * kHD + part * 32);
    float acc = 0.f;
#pragma unroll
    for (int i = 0; i < 8; ++i) {
      float4 kv = krow[i];
      float4 sv = srow[i];
      acc += rq[i].x * (kv.x + sv.x);
      acc += rq[i].y * (kv.y + sv.y);
      acc += rq[i].z * (kv.z + sv.z);
      acc += rq[i].w * (kv.w + sv.w);
    }
    // reduce the 4 lanes covering this query (lanes 4*qi .. 4*qi+3)
    acc += __shfl_xor(acc, 1);
    acc += __shfl_xor(acc, 2);
    const float sj = acc * kScale + s_pb[j];
    sc[j] = (n >= delta) ? sj : -INFINITY;
  }

  // ---- softmax over the J offsets (all 4 lanes compute it redundantly)
  float m = -INFINITY;
#pragma unroll
  for (int j = 0; j < kJ; ++j) m = fmaxf(m, sc[j]);
  const float msafe = (m == -INFINITY) ? 0.f : m;
  float l = 0.f;
  float p[kJ];
#pragma unroll
  for (int j = 0; j < kJ; ++j) {
    const float e = (sc[j] == -INFINITY) ? 0.f : __expf(sc[j] - msafe);
    p[j] = e;
    l += e;
  }
  const float inv = (l > 0.f) ? 1.f / l : 0.f;  // n==0 row -> all-zero output

  // ---- Phase B: out[n, part*32 .. +32) = sum_j p_j * v[n-dj]
  float4 o[8];
#pragma unroll
  for (int i = 0; i < 8; ++i) o[i] = make_float4(0.f, 0.f, 0.f, 0.f);
#pragma unroll
  for (int j = 0; j < kJ; ++j) {
    const float pj = p[j] * inv;
    int vr = n - OFFS[j];
    vr = vr < 0 ? 0 : vr;
    const float4* vrow = (const float4*)(v + base + (size_t)vr * kHD + part * 32);
#pragma unroll
    for (int i = 0; i < 8; ++i) {
      float4 vv = vrow[i];
      o[i].x += pj * vv.x;
      o[i].y += pj * vv.y;
      o[i].z += pj * vv.z;
      o[i].w += pj * vv.w;
    }
  }
  float4* orow = (float4*)(out + base + (size_t)n * kHD + part * 32);
#pragma unroll
  for (int i = 0; i < 8; ++i) orow[i] = o[i];
}

}  // namespace

extern "C" void kernel_launch(void* const* d_in, const int* in_sizes, int n_in,
                              void* d_out, int out_size, void* d_ws, size_t ws_size,
                              hipStream_t stream) {
  const float* q = (const float*)d_in[0];
  const float* k = (const float*)d_in[1];
  const float* v = (const float*)d_in[2];
  const float* pb = (const float*)d_in[3];   // [J,H]
  const float* se = (const float*)d_in[4];   // [J,HD]
  float* out = (float*)d_out;

  dim3 grid(kN / kTQ, kB * kH);  // 128 query-tiles x 32 (b,h) = 4096 blocks
  dsqg_fwd<<<grid, 256, 0, stream>>>(q, k, v, pb, se, out);
}

// Round 2
// 760.647 us; speedup vs baseline: 1.2777x; 1.2777x over previous
//
#include <hip/hip_runtime.h>
#include <math.h>

namespace {

constexpr int kB = 2, kH = 16, kN = 8192, kHD = 128, kJ = 20;
constexpr int kTQ = 64;                         // queries per 256-thread block (4 lanes/query)
constexpr float kScale = 0.08838834764831845f;  // 1/sqrt(128)

// Lane mapping: t>>2 = query, t&3 = part. Lane `part` owns float4 chunks
// {i*4 + part : i in 0..7} — so each wave-level load instruction i covers a
// CONTIGUOUS 64B span per 4-lane group (16 unique cache lines/instr, the
// minimum), instead of the 128B-strided pattern (64 lines/instr) that made
// round-1 TA-throughput-bound at 7.5% VALUBusy / 12% HBM.
__global__ __launch_bounds__(256, 4)
void dsqg_fwd(const float* __restrict__ q, const float* __restrict__ k,
              const float* __restrict__ v, const float* __restrict__ pb,
              const float* __restrict__ se, float* __restrict__ out) {
  constexpr int OFFS[kJ] = {1, 2, 3, 4, 5, 6, 7, 8, 9, 11,
                            13, 15, 16, 23, 32, 64, 128, 256, 512, 1024};
  __shared__ float s_se[kJ * kHD];  // 10 KB
  __shared__ float s_pb[kJ];

  const int t = threadIdx.x;
  const int bh = blockIdx.y;        // b*H + h
  const int h = bh & (kH - 1);
  const int n = blockIdx.x * kTQ + (t >> 2);
  const int part = t & 3;

  for (int i = t; i < kJ * kHD; i += 256) s_se[i] = se[i];
  if (t < kJ) s_pb[t] = pb[t * kH + h];
  __syncthreads();

  const size_t base = (size_t)bh * kN * kHD;
  const float4* qrow = (const float4*)(q + base + (size_t)n * kHD);
  float4 rq[8];
#pragma unroll
  for (int i = 0; i < 8; ++i) rq[i] = qrow[i * 4 + part];

  // ---- Phase A: s_j = sc*(q.(k[n-dj]+se_j)) + pb[j][h], -inf if n<dj
  float sc[kJ];
#pragma unroll
  for (int j = 0; j < kJ; ++j) {
    const int delta = OFFS[j];
    int kr = n - delta;
    kr = kr < 0 ? 0 : kr;
    const float4* krow = (const float4*)(k + base + (size_t)kr * kHD);
    const float4* srow = (const float4*)(s_se + j * kHD);
    float acc = 0.f;
#pragma unroll
    for (int i = 0; i < 8; ++i) {
      float4 kv = krow[i * 4 + part];
      float4 sv = srow[i * 4 + part];
      acc += rq[i].x * (kv.x + sv.x);
      acc += rq[i].y * (kv.y + sv.y);
      acc += rq[i].z * (kv.z + sv.z);
      acc += rq[i].w * (kv.w + sv.w);
    }
    acc += __shfl_xor(acc, 1);
    acc += __shfl_xor(acc, 2);
    const float sj = acc * kScale + s_pb[j];
    sc[j] = (n >= delta) ? sj : -INFINITY;
  }

  // ---- softmax over J (redundant in the 4 lanes)
  float m = -INFINITY;
#pragma unroll
  for (int j = 0; j < kJ; ++j) m = fmaxf(m, sc[j]);
  const float msafe = (m == -INFINITY) ? 0.f : m;
  float l = 0.f;
#pragma unroll
  for (int j = 0; j < kJ; ++j) {
    const float e = (sc[j] == -INFINITY) ? 0.f : __expf(sc[j] - msafe);
    sc[j] = e;  // reuse: sc now holds unnormalized p
    l += e;
  }
  const float inv = (l > 0.f) ? 1.f / l : 0.f;  // n==0 -> zero output

  // ---- Phase B: out = sum_j p_j * v[n-dj]
  float4 o[8];
#pragma unroll
  for (int i = 0; i < 8; ++i) o[i] = make_float4(0.f, 0.f, 0.f, 0.f);
#pragma unroll
  for (int j = 0; j < kJ; ++j) {
    const float pj = sc[j] * inv;
    int vr = n - OFFS[j];
    vr = vr < 0 ? 0 : vr;
    const float4* vrow = (const float4*)(v + base + (size_t)vr * kHD);
#pragma unroll
    for (int i = 0; i < 8; ++i) {
      float4 vv = vrow[i * 4 + part];
      o[i].x += pj * vv.x;
      o[i].y += pj * vv.y;
      o[i].z += pj * vv.z;
      o[i].w += pj * vv.w;
    }
  }
  float4* orow = (float4*)(out + base + (size_t)n * kHD);
#pragma unroll
  for (int i = 0; i < 8; ++i) orow[i * 4 + part] = o[i];
}

}  // namespace

extern "C" void kernel_launch(void* const* d_in, const int* in_sizes, int n_in,
                              void* d_out, int out_size, void* d_ws, size_t ws_size,
                              hipStream_t stream) {
  const float* q = (const float*)d_in[0];
  const float* k = (const float*)d_in[1];
  const float* v = (const float*)d_in[2];
  const float* pb = (const float*)d_in[3];   // [J,H]
  const float* se = (const float*)d_in[4];   // [J,HD]
  float* out = (float*)d_out;

  dim3 grid(kN / kTQ, kB * kH);  // 128 x 32 = 4096 blocks
  dsqg_fwd<<<grid, 256, 0, stream>>>(q, k, v, pb, se, out);
}